// Round 3
// baseline (370.039 us; speedup 1.0000x reference)
//
#include <hip/hip_runtime.h>

// VanillaRNN: S=512, I=1, H=256, C=10, B=2048, fp32 in/out.
// R9: two-phase software pipeline. R8 post-mortem: SQ_LDS_BANK_CONFLICT is a
// ds_read_b128 multi-pass artifact (same ~5cyc/instr across 3 swizzles), and
// step time 1490cy == LDS 768 + MFMA 620 + tanh ~400 + barrier == phases
// fully SERIALIZED. Fix = overlap, not smaller phases:
//   wave w owns tiles T0=w (rows 16w..16w+15) and T1=w+8 (rows 128+16w..).
//   => all waves' T0 writes == lower K-half of h_{t+1}, T1 == upper half.
//   P1: issue upper-half reads of h_t  || MFMA mt0 (lower from regs, then
//       upper as returns arrive), tanh+write mt0, barrier.
//   P2: prefetch lower-half reads of h_{t+1} (just completed at B1)
//       || MFMA mt1 (all operands in regs), tanh+write mt1, barrier.
//   Each 384cy read window hides under a ~450cy compute window.
// Reverted R8's acc0/acc1 split (regression suspect): single 8-deep chains.
// Swizzle kept (free): chunk c of row n at c ^ sw(n), sw=(n&7)^((n>>3)<<2);
// XOR touches only low 3 chunk bits -> K-halves map to themselves (the
// pipeline's "half written" invariant survives the swizzle).
// Weights pre-scaled by 2*log2e: tanh = 1 - 2*rcp(exp2(s)+1).

#define SEQ    512
#define HID    256
#define NCLS   10
#define BN     16     // batch per block
#define NT     512    // 8 waves
#define XP     17     // xs row pitch

typedef _Float16 f16x8 __attribute__((ext_vector_type(8)));
typedef _Float16 f16x4 __attribute__((ext_vector_type(4)));
typedef float    f32x4 __attribute__((ext_vector_type(4)));

#define MFMA16(a, b, c) __builtin_amdgcn_mfma_f32_16x16x32_f16(a, b, c, 0, 0, 0)

__global__ __launch_bounds__(NT)
__attribute__((amdgpu_waves_per_eu(2, 2)))
void rnn_mfma(
    const float* __restrict__ x,     // [B, S]
    const float* __restrict__ W_hx,  // [H]
    const float* __restrict__ W_hh,  // [H, H]
    const float* __restrict__ W_ph,  // [C, H]
    const float* __restrict__ b_h,   // [H]
    const float* __restrict__ b_p,   // [C]
    float* __restrict__ out)         // [B, C]
{
    __shared__ __align__(16) _Float16 hT[2][BN][HID];   // 16 KB
    __shared__ __align__(16) float xs[SEQ + 2][XP];     // 34.9 KB

    const int tid  = threadIdx.x;
    const int lane = tid & 63;
    const int wave = tid >> 6;       // 0..7
    const int n16  = lane & 15;
    const int quad = lane >> 4;      // 0..3
    const int sw   = (n16 & 7) ^ ((n16 >> 3) << 2);
    const int b0   = blockIdx.x * BN;

    const float SC = 2.885390081777926814f;   // 2*log2(e)

    // ---- A-frags: tiles T = wave + 8*mt, rows T*16 + n16, scaled, f16 ----
    f16x8 afrag[2][8];
#pragma unroll
    for (int mt = 0; mt < 2; ++mt) {
        const int row = (wave + 8 * mt) * 16 + n16;
#pragma unroll
        for (int ks = 0; ks < 8; ++ks) {
            const float4* p = (const float4*)&W_hh[row * HID + ks * 32 + quad * 8];
            float4 u = p[0], v = p[1];
            f16x8 a;
            a[0] = (_Float16)(SC * u.x); a[1] = (_Float16)(SC * u.y);
            a[2] = (_Float16)(SC * u.z); a[3] = (_Float16)(SC * u.w);
            a[4] = (_Float16)(SC * v.x); a[5] = (_Float16)(SC * v.y);
            a[6] = (_Float16)(SC * v.z); a[7] = (_Float16)(SC * v.w);
            afrag[mt][ks] = a;
        }
    }
    // D rows for this lane: row = (wave+8*mt)*16 + quad*4 + r
    f32x4 bias[2], wxv[2];
#pragma unroll
    for (int mt = 0; mt < 2; ++mt)
#pragma unroll
        for (int r = 0; r < 4; ++r) {
            const int row = (wave + 8 * mt) * 16 + quad * 4 + r;
            bias[mt][r] = SC * b_h[row];
            wxv[mt][r]  = SC * W_hx[row];
        }

    // ---- swizzled byte offsets ----
    int roff[8], woff[2];
#pragma unroll
    for (int ks = 0; ks < 8; ++ks)
        roff[ks] = (n16 * HID + (((4 * ks + quad) ^ sw) << 3)) * 2;
#pragma unroll
    for (int mt = 0; mt < 2; ++mt)
        woff[mt] = (n16 * HID +
                    (((2 * (wave + 8 * mt) + (quad >> 1)) ^ sw) << 3) +
                    (quad & 1) * 4) * 2;

    // ---- stage xs[t][n] = x[b0+n][t] ----
    for (int i = tid; i < BN * SEQ / 4; i += NT) {
        const int n = i >> 7, t4 = (i & 127) * 4;
        float4 v = *(const float4*)&x[(b0 + n) * SEQ + t4];
        xs[t4 + 0][n] = v.x; xs[t4 + 1][n] = v.y;
        xs[t4 + 2][n] = v.z; xs[t4 + 3][n] = v.w;
    }
    // ---- h0 = 0 (buffer 0; buffer 1 fully written each odd step) ----
    for (int i = tid; i < BN * HID / 2; i += NT) ((float*)hT[0])[i] = 0.0f;
    __syncthreads();

    float xv = xs[0][n16];

    // prologue: lower half of h_0 into regs
    f16x8 bA[4], bB[4];
#pragma unroll
    for (int k = 0; k < 4; ++k)
        bA[k] = *(const f16x8*)((const char*)hT[0] + roff[k]);

#define TANH_WRITE(ACC, MT)                                                   \
    {                                                                         \
        f16x4 h4;                                                             \
        _Pragma("unroll")                                                     \
        for (int r = 0; r < 4; ++r) {                                         \
            float ex = __builtin_amdgcn_exp2f(ACC[r]);                        \
            float rc = __builtin_amdgcn_rcpf(ex + 1.0f);                      \
            h4[r] = (_Float16)(1.0f - 2.0f * rc);                             \
        }                                                                     \
        *(f16x4*)(wb + woff[MT]) = h4;                                        \
    }

#define RNN_STEP(T, RD, WR, LI, LO)                                           \
    {                                                                         \
        const float xnxt = xs[(T) + 1][n16];                                  \
        const char* rb = (const char*)hT[RD];                                 \
        char*       wb = (char*)hT[WR];                                       \
        /* P1: upper-half reads of h_t in flight under mt0's lower MFMAs */   \
        f16x8 hi0 = *(const f16x8*)(rb + roff[4]);                            \
        f16x8 hi1 = *(const f16x8*)(rb + roff[5]);                            \
        f16x8 hi2 = *(const f16x8*)(rb + roff[6]);                            \
        f16x8 hi3 = *(const f16x8*)(rb + roff[7]);                            \
        f32x4 acc;                                                            \
        _Pragma("unroll")                                                     \
        for (int r = 0; r < 4; ++r)                                           \
            acc[r] = fmaf(wxv[0][r], xv, bias[0][r]);                         \
        acc = MFMA16(afrag[0][0], LI[0], acc);                                \
        acc = MFMA16(afrag[0][1], LI[1], acc);                                \
        acc = MFMA16(afrag[0][2], LI[2], acc);                                \
        acc = MFMA16(afrag[0][3], LI[3], acc);                                \
        acc = MFMA16(afrag[0][4], hi0, acc);                                  \
        acc = MFMA16(afrag[0][5], hi1, acc);                                  \
        acc = MFMA16(afrag[0][6], hi2, acc);                                  \
        acc = MFMA16(afrag[0][7], hi3, acc);                                  \
        TANH_WRITE(acc, 0)                                                    \
        __syncthreads();  /* B1: lower half of h_{t+1} complete */            \
        /* P2: prefetch lower half of h_{t+1} under mt1's MFMAs+tanh */       \
        LO[0] = *(const f16x8*)((const char*)hT[WR] + roff[0]);               \
        LO[1] = *(const f16x8*)((const char*)hT[WR] + roff[1]);               \
        LO[2] = *(const f16x8*)((const char*)hT[WR] + roff[2]);               \
        LO[3] = *(const f16x8*)((const char*)hT[WR] + roff[3]);               \
        f32x4 acd;                                                            \
        _Pragma("unroll")                                                     \
        for (int r = 0; r < 4; ++r)                                           \
            acd[r] = fmaf(wxv[1][r], xv, bias[1][r]);                         \
        acd = MFMA16(afrag[1][0], LI[0], acd);                                \
        acd = MFMA16(afrag[1][1], LI[1], acd);                                \
        acd = MFMA16(afrag[1][2], LI[2], acd);                                \
        acd = MFMA16(afrag[1][3], LI[3], acd);                                \
        acd = MFMA16(afrag[1][4], hi0, acd);                                  \
        acd = MFMA16(afrag[1][5], hi1, acd);                                  \
        acd = MFMA16(afrag[1][6], hi2, acd);                                  \
        acd = MFMA16(afrag[1][7], hi3, acd);                                  \
        TANH_WRITE(acd, 1)                                                    \
        xv = xnxt;                                                            \
        __syncthreads();  /* B2: upper half of h_{t+1} complete */            \
    }

    for (int t = 0; t < SEQ; t += 2) {
        RNN_STEP(t,     0, 1, bA, bB);
        RNN_STEP(t + 1, 1, 0, bB, bA);
    }
#undef RNN_STEP
#undef TANH_WRITE

    // ---- output: out[b][c] = b_p[c] + sum_j W_ph[c][j] * h_final[j][b] ----
    // final h in hT[0]; element (n=b, k=j) at chunk (j>>3) ^ sw(b)
    if (tid < BN * NCLS) {
        const int b = tid / NCLS, c = tid % NCLS;
        const int sb = (b & 7) ^ ((b >> 3) << 2);
        float sum = b_p[c];
        const _Float16* hp = hT[0][b];
        for (int j = 0; j < HID; ++j) {
            const int ph = ((((j >> 3) ^ sb) << 3) | (j & 7));
            sum += W_ph[c * HID + j] * (float)hp[ph];
        }
        out[(b0 + b) * NCLS + c] = sum;
    }
}

extern "C" void kernel_launch(void* const* d_in, const int* in_sizes, int n_in,
                              void* d_out, int out_size, void* d_ws, size_t ws_size,
                              hipStream_t stream) {
    const float* x    = (const float*)d_in[0];
    const float* W_hx = (const float*)d_in[1];
    const float* W_hh = (const float*)d_in[2];
    const float* W_ph = (const float*)d_in[3];
    const float* b_h  = (const float*)d_in[4];
    const float* b_p  = (const float*)d_in[5];
    float* out = (float*)d_out;

    rnn_mfma<<<dim3(2048 / BN), dim3(NT), 0, stream>>>(
        x, W_hx, W_hh, W_ph, b_h, b_p, out);
}